// Round 6
// baseline (576.536 us; speedup 1.0000x reference)
//
#include <hip/hip_runtime.h>

#define N_NODES 50000
#define N_REL 16
#define D 128
#define N_SEG (N_NODES * N_REL)  // 800000

typedef short bf16x8 __attribute__((ext_vector_type(8)));
typedef float f32x4 __attribute__((ext_vector_type(4)));
typedef unsigned short u16;
typedef unsigned int u32;

__device__ __forceinline__ u16 f32_to_bf16(float f) {
  u32 u = __builtin_bit_cast(u32, f);
  u32 r = (u + 0x7FFFu + ((u >> 16) & 1u)) >> 16;
  return (u16)r;
}
__device__ __forceinline__ float bf16_to_f32(u16 h) {
  u32 u = ((u32)h) << 16;
  return __builtin_bit_cast(float, u);
}

// ---------------- zero (uint4 grid-stride) ----------------
__global__ __launch_bounds__(256) void k_zero4(uint4* __restrict__ p, long long n4) {
  long long i = (long long)blockIdx.x * blockDim.x + threadIdx.x;
  long long stride = (long long)gridDim.x * blockDim.x;
  uint4 z; z.x = z.y = z.z = z.w = 0u;
  for (; i < n4; i += stride) p[i] = z;
}

// ---------------- per-(dst,rel) edge counts ----------------
__global__ __launch_bounds__(256) void k_count(const int* __restrict__ dst,
                                               const int* __restrict__ rel,
                                               int* __restrict__ cnt, int E) {
  int e = blockIdx.x * blockDim.x + threadIdx.x;
  if (e < E) atomicAdd(&cnt[dst[e] * N_REL + rel[e]], 1);
}

// ---------------- scan: per-block sums ----------------
__global__ __launch_bounds__(256) void k_bsum(const int* __restrict__ cnt,
                                              int* __restrict__ bsum, int n) {
  __shared__ int sm[256];
  int i = blockIdx.x * 256 + threadIdx.x;
  int v = (i < n) ? cnt[i] : 0;
  sm[threadIdx.x] = v;
  __syncthreads();
  for (int s = 128; s > 0; s >>= 1) {
    if (threadIdx.x < s) sm[threadIdx.x] += sm[threadIdx.x + s];
    __syncthreads();
  }
  if (threadIdx.x == 0) bsum[blockIdx.x] = sm[0];
}

// ---------------- scan: single-block exclusive scan of block sums ----------------
__global__ __launch_bounds__(1024) void k_bscan(int* __restrict__ bsum, int nb) {
  __shared__ int sm[1024];
  __shared__ int carry;
  if (threadIdx.x == 0) carry = 0;
  __syncthreads();
  int niter = (nb + 1023) / 1024;
  for (int it = 0; it < niter; ++it) {
    int i = it * 1024 + threadIdx.x;
    int v = (i < nb) ? bsum[i] : 0;
    sm[threadIdx.x] = v;
    __syncthreads();
    for (int s = 1; s < 1024; s <<= 1) {
      int t = (threadIdx.x >= s) ? sm[threadIdx.x - s] : 0;
      __syncthreads();
      sm[threadIdx.x] += t;
      __syncthreads();
    }
    int incl = sm[threadIdx.x];
    int c = carry;
    __syncthreads();
    if (i < nb) bsum[i] = c + incl - v;
    if (threadIdx.x == 1023) carry = c + sm[1023];
    __syncthreads();
  }
}

// ---------------- scan: per-element exclusive offsets ----------------
__global__ __launch_bounds__(256) void k_off(const int* __restrict__ cnt,
                                             const int* __restrict__ bsum,
                                             int* __restrict__ off, int n) {
  __shared__ int sm[256];
  int i = blockIdx.x * 256 + threadIdx.x;
  int v = (i < n) ? cnt[i] : 0;
  sm[threadIdx.x] = v;
  __syncthreads();
  for (int s = 1; s < 256; s <<= 1) {
    int t = (threadIdx.x >= s) ? sm[threadIdx.x - s] : 0;
    __syncthreads();
    sm[threadIdx.x] += t;
    __syncthreads();
  }
  int excl = sm[threadIdx.x] - v + bsum[blockIdx.x];
  if (i < n) off[i] = excl;
  if (i == n - 1) off[n] = excl + v;
}

// ---------------- CSR fill (countdown — cnt is dead after k_off) ----------------
__global__ __launch_bounds__(256) void k_fill(const int* __restrict__ src,
                                              const int* __restrict__ dst,
                                              const int* __restrict__ rel,
                                              const int* __restrict__ off,
                                              int* __restrict__ cnt,
                                              int* __restrict__ bucket, int E) {
  int e = blockIdx.x * blockDim.x + threadIdx.x;
  if (e >= E) return;
  int seg = dst[e] * N_REL + rel[e];
  int old = atomicSub(&cnt[seg], 1);          // old in [1, cnt]
  bucket[off[seg] + old - 1] = src[e];
}

// ---------------- fused prep: f32->bf16 convert + all 4 weight-frag builds ----------
__device__ __forceinline__ void wfrag_one(const float* __restrict__ W,
                                          u16* __restrict__ Wf, int tid) {
  int lane = tid & 63;
  int t = (tid >> 6) & 7;
  int kb = tid >> 9;
  int h = t * 16 + (lane & 15);
  int kbase = kb * 32 + ((lane >> 4) << 3);
  bf16x8 frag;
#pragma unroll
  for (int j = 0; j < 8; ++j) {
    int k = kbase + j;
    frag[j] = (short)f32_to_bf16(W[(size_t)(k >> 7) * (D * D) + (size_t)(k & 127) * D + h]);
  }
  *(bf16x8*)(Wf + (size_t)tid * 8) = frag;
}

#define CVT_N4 (N_NODES * D / 4)         // 1,600,000
#define WF_T (64 * 8 * 64)               // 32768
#define RF_T (4 * 8 * 64)                // 2048
#define PREP_TOTAL (CVT_N4 + 2 * WF_T + 2 * RF_T)

__global__ __launch_bounds__(256) void k_prep(const float* __restrict__ emb,
                                              u16* __restrict__ embb,
                                              const float* __restrict__ W1,
                                              u16* __restrict__ Wf1,
                                              const float* __restrict__ W2,
                                              u16* __restrict__ Wf2,
                                              const float* __restrict__ R1,
                                              u16* __restrict__ Rf1,
                                              const float* __restrict__ R2,
                                              u16* __restrict__ Rf2,
                                              int* __restrict__ bucket, int E) {
  int tid = blockIdx.x * blockDim.x + threadIdx.x;
  if (tid == 0) bucket[E] = 0;       // slack slot for unconditional index prefetch
  if (tid < CVT_N4) {
    float4 v = ((const float4*)emb)[tid];
    u32 p0 = (u32)f32_to_bf16(v.x) | ((u32)f32_to_bf16(v.y) << 16);
    u32 p1 = (u32)f32_to_bf16(v.z) | ((u32)f32_to_bf16(v.w) << 16);
    ((u32*)embb)[tid * 2] = p0;
    ((u32*)embb)[tid * 2 + 1] = p1;
    return;
  }
  int u = tid - CVT_N4;
  if (u < WF_T) { wfrag_one(W1, Wf1, u); return; }
  u -= WF_T;
  if (u < WF_T) { wfrag_one(W2, Wf2, u); return; }
  u -= WF_T;
  if (u < RF_T) { wfrag_one(R1, Rf1, u); return; }
  u -= RF_T;
  if (u < RF_T) { wfrag_one(R2, Rf2, u); return; }
}

// ---------------- fused RGCN layer (v1 skeleton; R5 + R6 depth-2 pipeline) ---------
// One 16-node M-tile per BLOCK, 4 waves, each owning 4 relations + 1 kb-quarter
// of the root term; gather-mean straight into A-fragment registers; MFMA vs
// frag-linear Wf; 16KB two-round LDS reduce; fused bias(+ReLU)+store.
// R6: depth-2 software pipeline on the gather — edge i+1's 4 row-loads are in
// flight while edge i accumulates (guarded, no junk traffic); per-relation
// first-edge index hoisted above the root MFMA so its latency hides there.
// Register budget: ~76 arch + 32 acc ≈ 108 < 128 -> stays in 16-wave/CU bucket.
template <int L>  // L=1: bf16 out + ReLU; L=2: f32 out
__global__ __launch_bounds__(256) void k_layer(const int* __restrict__ off,
                                               const int* __restrict__ bucket,
                                               const u16* __restrict__ x,    // [N,128] bf16
                                               const u16* __restrict__ Wf,   // 64 kb frag-linear
                                               const u16* __restrict__ Rf,   // 4 kb frag-linear
                                               const float* __restrict__ bias,
                                               u16* __restrict__ outb,
                                               float* __restrict__ outf) {
  __shared__ f32x4 red[4][4][64];      // 16 KB
  int w = threadIdx.x >> 6;            // wave 0..3
  int lane = threadIdx.x & 63;
  int node0 = blockIdx.x << 4;         // 50000 = 3125*16, exact grid
  int m = lane & 15;
  int q = lane >> 4;
  int node = node0 + m;                // A-row this lane serves

  f32x4 acc[8];
#pragma unroll
  for (int t = 0; t < 8; ++t)
#pragma unroll
    for (int i = 0; i < 4; ++i) acc[t][i] = 0.0f;

  // ---- hoist this wave's 5 CSR offsets + first edge index per relation ----
  int segb = (node << 4) + (w << 2);
  int o_0 = off[segb];
  int o_1 = off[segb + 1];
  int o_2 = off[segb + 2];
  int o_3 = off[segb + 3];
  int o_4 = off[segb + 4];
  int sf0 = (o_0 < o_1) ? bucket[o_0] : 0;
  int sf1 = (o_1 < o_2) ? bucket[o_1] : 0;
  int sf2 = (o_2 < o_3) ? bucket[o_2] : 0;
  int sf3 = (o_3 < o_4) ? bucket[o_3] : 0;

  // ---- root term: this wave does kb = w (first-edge latency hides here) ----
  {
    bf16x8 a = *(const bf16x8*)(x + ((size_t)node << 7) + w * 32 + (q << 3));
    const u16* bp = Rf + ((size_t)w << 12) + ((size_t)lane << 3);
#pragma unroll
    for (int t = 0; t < 8; ++t) {
      bf16x8 b = *(const bf16x8*)(bp + t * 512);
      acc[t] = __builtin_amdgcn_mfma_f32_16x16x32_bf16(a, b, acc[t], 0, 0, 0);
    }
  }

  // ---- one relation: depth-2 pipelined gather-mean, then MFMA vs W_r ----
  auto do_rel = [&](int r, int lo, int hi, int sf) {
    float a0[8], a1[8], a2[8], a3[8];
#pragma unroll
    for (int j = 0; j < 8; ++j) { a0[j] = 0.f; a1[j] = 0.f; a2[j] = 0.f; a3[j] = 0.f; }

    int i = lo;
    bf16x8 v0, v1, v2, v3;
    if (i < hi) {                       // preload edge lo's rows (sf hoisted)
      const u16* xs = x + ((size_t)sf << 7) + (q << 3);
      v0 = *(const bf16x8*)(xs);
      v1 = *(const bf16x8*)(xs + 32);
      v2 = *(const bf16x8*)(xs + 64);
      v3 = *(const bf16x8*)(xs + 96);
    }
    for (; i < hi; ++i) {               // divergent across m; exec-masked
      if (i + 1 < hi) {                 // prefetch edge i+1's rows (no junk traffic)
        int sn = bucket[i + 1];
        const u16* xn = x + ((size_t)sn << 7) + (q << 3);
        bf16x8 n0 = *(const bf16x8*)(xn);
        bf16x8 n1 = *(const bf16x8*)(xn + 32);
        bf16x8 n2 = *(const bf16x8*)(xn + 64);
        bf16x8 n3 = *(const bf16x8*)(xn + 96);
#pragma unroll
        for (int j = 0; j < 8; ++j) {
          a0[j] += bf16_to_f32((u16)v0[j]);
          a1[j] += bf16_to_f32((u16)v1[j]);
          a2[j] += bf16_to_f32((u16)v2[j]);
          a3[j] += bf16_to_f32((u16)v3[j]);
        }
        v0 = n0; v1 = n1; v2 = n2; v3 = n3;
      } else {                          // last edge: just accumulate
#pragma unroll
        for (int j = 0; j < 8; ++j) {
          a0[j] += bf16_to_f32((u16)v0[j]);
          a1[j] += bf16_to_f32((u16)v1[j]);
          a2[j] += bf16_to_f32((u16)v2[j]);
          a3[j] += bf16_to_f32((u16)v3[j]);
        }
      }
    }

    float sc = (hi > lo) ? 1.0f / (float)(hi - lo) : 0.0f;
    bf16x8 f0, f1, f2, f3;
#pragma unroll
    for (int j = 0; j < 8; ++j) {
      f0[j] = (short)f32_to_bf16(a0[j] * sc);
      f1[j] = (short)f32_to_bf16(a1[j] * sc);
      f2[j] = (short)f32_to_bf16(a2[j] * sc);
      f3[j] = (short)f32_to_bf16(a3[j] * sc);
    }

    const u16* bp = Wf + ((size_t)(r * 4) << 12) + ((size_t)lane << 3);
#pragma unroll
    for (int t = 0; t < 8; ++t) {
      bf16x8 b0 = *(const bf16x8*)(bp + t * 512);
      bf16x8 b1 = *(const bf16x8*)(bp + 4096 + t * 512);
      bf16x8 b2 = *(const bf16x8*)(bp + 8192 + t * 512);
      bf16x8 b3 = *(const bf16x8*)(bp + 12288 + t * 512);
      acc[t] = __builtin_amdgcn_mfma_f32_16x16x32_bf16(f0, b0, acc[t], 0, 0, 0);
      acc[t] = __builtin_amdgcn_mfma_f32_16x16x32_bf16(f1, b1, acc[t], 0, 0, 0);
      acc[t] = __builtin_amdgcn_mfma_f32_16x16x32_bf16(f2, b2, acc[t], 0, 0, 0);
      acc[t] = __builtin_amdgcn_mfma_f32_16x16x32_bf16(f3, b3, acc[t], 0, 0, 0);
    }
  };

  int rbase = w << 2;
  do_rel(rbase + 0, o_0, o_1, sf0);
  do_rel(rbase + 1, o_1, o_2, sf1);
  do_rel(rbase + 2, o_2, o_3, sf2);
  do_rel(rbase + 3, o_3, o_4, sf3);

  // ---- two-round epilogue over 16KB red buffer ----
  // round h: waves write acc[4h..4h+3]; wave w reduces chunk t = 4h + w.
#pragma unroll
  for (int half = 0; half < 2; ++half) {
#pragma unroll
    for (int t = 0; t < 4; ++t) red[w][t][lane] = acc[half * 4 + t];
    __syncthreads();
    {
      f32x4 s0 = red[0][w][lane];
      f32x4 s1 = red[1][w][lane];
      f32x4 s2 = red[2][w][lane];
      f32x4 s3 = red[3][w][lane];
      int tt = half * 4 + w;
      int h = tt * 16 + m;             // C layout col=m, row=q*4+reg [m89]
      float bv = bias[h];
#pragma unroll
      for (int r4 = 0; r4 < 4; ++r4) {
        int n = node0 + (q << 2) + r4;
        float v = s0[r4] + s1[r4] + s2[r4] + s3[r4] + bv;
        if (L == 1) {
          v = v > 0.0f ? v : 0.0f;
          outb[(size_t)n * D + h] = f32_to_bf16(v);
        } else {
          outf[(size_t)n * D + h] = v;
        }
      }
    }
    if (half == 0) __syncthreads();    // WAR: round-A reads done before round-B writes
  }
}

extern "C" void kernel_launch(void* const* d_in, const int* in_sizes, int n_in,
                              void* d_out, int out_size, void* d_ws, size_t ws_size,
                              hipStream_t stream) {
  const int* edge_index = (const int*)d_in[0];
  const int* edge_type  = (const int*)d_in[1];
  const float* emb   = (const float*)d_in[2];
  const float* W1    = (const float*)d_in[3];
  const float* root1 = (const float*)d_in[4];
  const float* b1    = (const float*)d_in[5];
  const float* W2    = (const float*)d_in[6];
  const float* root2 = (const float*)d_in[7];
  const float* b2    = (const float*)d_in[8];
  float* out = (float*)d_out;

  int E = in_sizes[0] / 2;
  const int* src = edge_index;      // row 0
  const int* dst = edge_index + E;  // row 1
  int nblocks_seg = (N_SEG + 255) / 256;  // 3125

  char* ws = (char*)d_ws;
  size_t off_b = 0;
  auto take = [&](size_t bytes) -> char* {
    char* p = ws + off_b;
    off_b += (bytes + 255) & ~(size_t)255;
    return p;
  };
  int*   cnt    = (int*)take((size_t)N_SEG * 4);
  int*   offs   = (int*)take((size_t)(N_SEG + 1) * 4);
  int*   bsum   = (int*)take((size_t)nblocks_seg * 4);
  int*   bucket = (int*)take((size_t)(E + 1) * 4);   // +1 slack slot (zeroed in k_prep)
  u16*   embb   = (u16*)take((size_t)N_NODES * D * 2);
  u16*   x1     = (u16*)take((size_t)N_NODES * D * 2);
  u16*   Wf1    = (u16*)take((size_t)64 * 8 * 512 * 2);
  u16*   Rf1    = (u16*)take((size_t)4 * 8 * 512 * 2);
  u16*   Wf2    = (u16*)take((size_t)64 * 8 * 512 * 2);
  u16*   Rf2    = (u16*)take((size_t)4 * 8 * 512 * 2);
  // total ~41 MB — fits comfortably

  int eBlocks = (E + 255) / 256;
  int layerBlocks = N_NODES / 16;   // 3125 blocks, 1 tile per block

  // --- CSR build (shared by both layers) ---
  k_zero4<<<512, 256, 0, stream>>>((uint4*)cnt, (long long)N_SEG * 4 / 16);
  k_count<<<eBlocks, 256, 0, stream>>>(dst, edge_type, cnt, E);
  k_bsum<<<nblocks_seg, 256, 0, stream>>>(cnt, bsum, N_SEG);
  k_bscan<<<1, 1024, 0, stream>>>(bsum, nblocks_seg);
  k_off<<<nblocks_seg, 256, 0, stream>>>(cnt, bsum, offs, N_SEG);
  k_fill<<<eBlocks, 256, 0, stream>>>(src, dst, edge_type, offs, cnt, bucket, E);

  // --- fused weight/embedding prep (single launch; also zeroes bucket[E]) ---
  k_prep<<<(PREP_TOTAL + 255) / 256, 256, 0, stream>>>(emb, embb, W1, Wf1, W2, Wf2,
                                                       root1, Rf1, root2, Rf2,
                                                       bucket, E);

  // --- two fused layers ---
  k_layer<1><<<layerBlocks, 256, 0, stream>>>(offs, bucket, embb, Wf1, Rf1, b1,
                                              x1, nullptr);
  k_layer<2><<<layerBlocks, 256, 0, stream>>>(offs, bucket, x1, Wf2, Rf2, b2,
                                              nullptr, out);
}

// Round 8
// 528.586 us; speedup vs baseline: 1.0907x; 1.0907x over previous
//
#include <hip/hip_runtime.h>

#define N_NODES 50000
#define N_REL 16
#define D 128
#define N_SEG (N_NODES * N_REL)  // 800000

typedef short bf16x8 __attribute__((ext_vector_type(8)));
typedef float f32x4 __attribute__((ext_vector_type(4)));
typedef unsigned short u16;
typedef unsigned int u32;

__device__ __forceinline__ u16 f32_to_bf16(float f) {
  u32 u = __builtin_bit_cast(u32, f);
  u32 r = (u + 0x7FFFu + ((u >> 16) & 1u)) >> 16;
  return (u16)r;
}
__device__ __forceinline__ float bf16_to_f32(u16 h) {
  u32 u = ((u32)h) << 16;
  return __builtin_bit_cast(float, u);
}

// ---------------- zero (uint4 grid-stride) ----------------
__global__ __launch_bounds__(256) void k_zero4(uint4* __restrict__ p, long long n4) {
  long long i = (long long)blockIdx.x * blockDim.x + threadIdx.x;
  long long stride = (long long)gridDim.x * blockDim.x;
  uint4 z; z.x = z.y = z.z = z.w = 0u;
  for (; i < n4; i += stride) p[i] = z;
}

// ---------------- per-(dst,rel) edge counts ----------------
__global__ __launch_bounds__(256) void k_count(const int* __restrict__ dst,
                                               const int* __restrict__ rel,
                                               int* __restrict__ cnt, int E) {
  int e = blockIdx.x * blockDim.x + threadIdx.x;
  if (e < E) atomicAdd(&cnt[dst[e] * N_REL + rel[e]], 1);
}

// ---------------- scan: per-block sums ----------------
__global__ __launch_bounds__(256) void k_bsum(const int* __restrict__ cnt,
                                              int* __restrict__ bsum, int n) {
  __shared__ int sm[256];
  int i = blockIdx.x * 256 + threadIdx.x;
  int v = (i < n) ? cnt[i] : 0;
  sm[threadIdx.x] = v;
  __syncthreads();
  for (int s = 128; s > 0; s >>= 1) {
    if (threadIdx.x < s) sm[threadIdx.x] += sm[threadIdx.x + s];
    __syncthreads();
  }
  if (threadIdx.x == 0) bsum[blockIdx.x] = sm[0];
}

// ---------------- scan: single-block exclusive scan of block sums ----------------
__global__ __launch_bounds__(1024) void k_bscan(int* __restrict__ bsum, int nb) {
  __shared__ int sm[1024];
  __shared__ int carry;
  if (threadIdx.x == 0) carry = 0;
  __syncthreads();
  int niter = (nb + 1023) / 1024;
  for (int it = 0; it < niter; ++it) {
    int i = it * 1024 + threadIdx.x;
    int v = (i < nb) ? bsum[i] : 0;
    sm[threadIdx.x] = v;
    __syncthreads();
    for (int s = 1; s < 1024; s <<= 1) {
      int t = (threadIdx.x >= s) ? sm[threadIdx.x - s] : 0;
      __syncthreads();
      sm[threadIdx.x] += t;
      __syncthreads();
    }
    int incl = sm[threadIdx.x];
    int c = carry;
    __syncthreads();
    if (i < nb) bsum[i] = c + incl - v;
    if (threadIdx.x == 1023) carry = c + sm[1023];
    __syncthreads();
  }
}

// ---------------- scan: per-element exclusive offsets ----------------
__global__ __launch_bounds__(256) void k_off(const int* __restrict__ cnt,
                                             const int* __restrict__ bsum,
                                             int* __restrict__ off, int n) {
  __shared__ int sm[256];
  int i = blockIdx.x * 256 + threadIdx.x;
  int v = (i < n) ? cnt[i] : 0;
  sm[threadIdx.x] = v;
  __syncthreads();
  for (int s = 1; s < 256; s <<= 1) {
    int t = (threadIdx.x >= s) ? sm[threadIdx.x - s] : 0;
    __syncthreads();
    sm[threadIdx.x] += t;
    __syncthreads();
  }
  int excl = sm[threadIdx.x] - v + bsum[blockIdx.x];
  if (i < n) off[i] = excl;
  if (i == n - 1) off[n] = excl + v;
}

// ---------------- CSR fill (countdown — cnt is dead after k_off) ----------------
__global__ __launch_bounds__(256) void k_fill(const int* __restrict__ src,
                                              const int* __restrict__ dst,
                                              const int* __restrict__ rel,
                                              const int* __restrict__ off,
                                              int* __restrict__ cnt,
                                              int* __restrict__ bucket, int E) {
  int e = blockIdx.x * blockDim.x + threadIdx.x;
  if (e >= E) return;
  int seg = dst[e] * N_REL + rel[e];
  int old = atomicSub(&cnt[seg], 1);          // old in [1, cnt]
  bucket[off[seg] + old - 1] = src[e];
}

// ---------------- fused prep: f32->bf16 convert + all 4 weight-frag builds ----------
__device__ __forceinline__ void wfrag_one(const float* __restrict__ W,
                                          u16* __restrict__ Wf, int tid) {
  int lane = tid & 63;
  int t = (tid >> 6) & 7;
  int kb = tid >> 9;
  int h = t * 16 + (lane & 15);
  int kbase = kb * 32 + ((lane >> 4) << 3);
  bf16x8 frag;
#pragma unroll
  for (int j = 0; j < 8; ++j) {
    int k = kbase + j;
    frag[j] = (short)f32_to_bf16(W[(size_t)(k >> 7) * (D * D) + (size_t)(k & 127) * D + h]);
  }
  *(bf16x8*)(Wf + (size_t)tid * 8) = frag;
}

#define CVT_N4 (N_NODES * D / 4)         // 1,600,000
#define WF_T (64 * 8 * 64)               // 32768
#define RF_T (4 * 8 * 64)                // 2048
#define PREP_TOTAL (CVT_N4 + 2 * WF_T + 2 * RF_T)

__global__ __launch_bounds__(256) void k_prep(const float* __restrict__ emb,
                                              u16* __restrict__ embb,
                                              const float* __restrict__ W1,
                                              u16* __restrict__ Wf1,
                                              const float* __restrict__ W2,
                                              u16* __restrict__ Wf2,
                                              const float* __restrict__ R1,
                                              u16* __restrict__ Rf1,
                                              const float* __restrict__ R2,
                                              u16* __restrict__ Rf2) {
  int tid = blockIdx.x * blockDim.x + threadIdx.x;
  if (tid < CVT_N4) {
    float4 v = ((const float4*)emb)[tid];
    u32 p0 = (u32)f32_to_bf16(v.x) | ((u32)f32_to_bf16(v.y) << 16);
    u32 p1 = (u32)f32_to_bf16(v.z) | ((u32)f32_to_bf16(v.w) << 16);
    ((u32*)embb)[tid * 2] = p0;
    ((u32*)embb)[tid * 2 + 1] = p1;
    return;
  }
  int u = tid - CVT_N4;
  if (u < WF_T) { wfrag_one(W1, Wf1, u); return; }
  u -= WF_T;
  if (u < WF_T) { wfrag_one(W2, Wf2, u); return; }
  u -= WF_T;
  if (u < RF_T) { wfrag_one(R1, Rf1, u); return; }
  u -= RF_T;
  if (u < RF_T) { wfrag_one(R2, Rf2, u); return; }
}

// ---------------- fused RGCN layer (R7: 8-wave re-partition of the R5 skeleton) ----
// Insight (R5/R6 counters): occupancy was GRID-limited — 3125 blocks x 4 waves =
// 12.2 waves/CU = the measured 38%. This version keeps the R5 inner loops and
// traffic EXACTLY, but halves relations-per-wave: 512 threads, 8 waves, wave w
// owns relations {2w, 2w+1}; waves 0-3 also own root kb-quarter w. 25,000 waves
// = 24.4/CU = 76% ceiling -> 2x latency-hiding concurrency, same registers,
// same per-block Wf/L2 traffic. Epilogue: 2-round 8-way LDS reduce (32 KB).
template <int L>  // L=1: bf16 out + ReLU; L=2: f32 out
__global__ __launch_bounds__(512) void k_layer(const int* __restrict__ off,
                                               const int* __restrict__ bucket,
                                               const u16* __restrict__ x,    // [N,128] bf16
                                               const u16* __restrict__ Wf,   // 64 kb frag-linear
                                               const u16* __restrict__ Rf,   // 4 kb frag-linear
                                               const float* __restrict__ bias,
                                               u16* __restrict__ outb,
                                               float* __restrict__ outf) {
  __shared__ f32x4 red[8][4][64];      // 32 KB
  int w = threadIdx.x >> 6;            // wave 0..7
  int lane = threadIdx.x & 63;
  int node0 = blockIdx.x << 4;         // 50000 = 3125*16, exact grid
  int m = lane & 15;
  int q = lane >> 4;
  int node = node0 + m;                // A-row this lane serves

  f32x4 acc[8];
#pragma unroll
  for (int t = 0; t < 8; ++t)
#pragma unroll
    for (int i = 0; i < 4; ++i) acc[t][i] = 0.0f;

  // ---- hoist this wave's 3 CSR offsets (segs (node<<4)+2w .. +2) ----
  int segb = (node << 4) + (w << 1);
  int o_0 = off[segb];
  int o_1 = off[segb + 1];
  int o_2 = off[segb + 2];

  // ---- root term: waves 0..3 do kb = w (first-edge latency hides under it) ----
  if (w < 4) {
    bf16x8 a = *(const bf16x8*)(x + ((size_t)node << 7) + w * 32 + (q << 3));
    const u16* bp = Rf + ((size_t)w << 12) + ((size_t)lane << 3);
#pragma unroll
    for (int t = 0; t < 8; ++t) {
      bf16x8 b = *(const bf16x8*)(bp + t * 512);
      acc[t] = __builtin_amdgcn_mfma_f32_16x16x32_bf16(a, b, acc[t], 0, 0, 0);
    }
  }

  // ---- one relation: R5 rotated-index gather-mean, then MFMA vs W_r ----
  auto do_rel = [&](int r, int lo, int hi) {
    float a0[8], a1[8], a2[8], a3[8];
#pragma unroll
    for (int j = 0; j < 8; ++j) { a0[j] = 0.f; a1[j] = 0.f; a2[j] = 0.f; a3[j] = 0.f; }

    // rotated prefetch: bucket[i+1] in flight while edge i's rows load/accumulate
    int i = lo;
    int s = (i < hi) ? bucket[i] : 0;
    while (i < hi) {                   // divergent across m; exec-masked
      const u16* xs = x + ((size_t)s << 7) + (q << 3);
      bf16x8 v0 = *(const bf16x8*)(xs);
      bf16x8 v1 = *(const bf16x8*)(xs + 32);
      bf16x8 v2 = *(const bf16x8*)(xs + 64);
      bf16x8 v3 = *(const bf16x8*)(xs + 96);
      int snext = (i + 1 < hi) ? bucket[i + 1] : 0;
#pragma unroll
      for (int j = 0; j < 8; ++j) {
        a0[j] += bf16_to_f32((u16)v0[j]);
        a1[j] += bf16_to_f32((u16)v1[j]);
        a2[j] += bf16_to_f32((u16)v2[j]);
        a3[j] += bf16_to_f32((u16)v3[j]);
      }
      s = snext;
      ++i;
    }

    float sc = (hi > lo) ? 1.0f / (float)(hi - lo) : 0.0f;
    bf16x8 f0, f1, f2, f3;
#pragma unroll
    for (int j = 0; j < 8; ++j) {
      f0[j] = (short)f32_to_bf16(a0[j] * sc);
      f1[j] = (short)f32_to_bf16(a1[j] * sc);
      f2[j] = (short)f32_to_bf16(a2[j] * sc);
      f3[j] = (short)f32_to_bf16(a3[j] * sc);
    }

    const u16* bp = Wf + ((size_t)(r * 4) << 12) + ((size_t)lane << 3);
#pragma unroll
    for (int t = 0; t < 8; ++t) {
      bf16x8 b0 = *(const bf16x8*)(bp + t * 512);
      bf16x8 b1 = *(const bf16x8*)(bp + 4096 + t * 512);
      bf16x8 b2 = *(const bf16x8*)(bp + 8192 + t * 512);
      bf16x8 b3 = *(const bf16x8*)(bp + 12288 + t * 512);
      acc[t] = __builtin_amdgcn_mfma_f32_16x16x32_bf16(f0, b0, acc[t], 0, 0, 0);
      acc[t] = __builtin_amdgcn_mfma_f32_16x16x32_bf16(f1, b1, acc[t], 0, 0, 0);
      acc[t] = __builtin_amdgcn_mfma_f32_16x16x32_bf16(f2, b2, acc[t], 0, 0, 0);
      acc[t] = __builtin_amdgcn_mfma_f32_16x16x32_bf16(f3, b3, acc[t], 0, 0, 0);
    }
  };

  int rbase = w << 1;
  do_rel(rbase + 0, o_0, o_1);
  do_rel(rbase + 1, o_1, o_2);

  // ---- 2-round epilogue: 8-way reduce over 32KB red buffer ----
  // round h: all waves write acc[4h..4h+3]; waves 0..3 reduce chunk t = 4h + w.
#pragma unroll
  for (int half = 0; half < 2; ++half) {
#pragma unroll
    for (int t = 0; t < 4; ++t) red[w][t][lane] = acc[half * 4 + t];
    __syncthreads();
    if (w < 4) {
      f32x4 s0 = red[0][w][lane];
      f32x4 s1 = red[1][w][lane];
      f32x4 s2 = red[2][w][lane];
      f32x4 s3 = red[3][w][lane];
      f32x4 s4 = red[4][w][lane];
      f32x4 s5 = red[5][w][lane];
      f32x4 s6 = red[6][w][lane];
      f32x4 s7 = red[7][w][lane];
      int tt = half * 4 + w;
      int h = tt * 16 + m;             // C layout col=m, row=q*4+reg [m89]
      float bv = bias[h];
#pragma unroll
      for (int r4 = 0; r4 < 4; ++r4) {
        int n = node0 + (q << 2) + r4;
        float v = s0[r4] + s1[r4] + s2[r4] + s3[r4] +
                  s4[r4] + s5[r4] + s6[r4] + s7[r4] + bv;
        if (L == 1) {
          v = v > 0.0f ? v : 0.0f;
          outb[(size_t)n * D + h] = f32_to_bf16(v);
        } else {
          outf[(size_t)n * D + h] = v;
        }
      }
    }
    if (half == 0) __syncthreads();    // WAR: round-A reads done before round-B writes
  }
}

extern "C" void kernel_launch(void* const* d_in, const int* in_sizes, int n_in,
                              void* d_out, int out_size, void* d_ws, size_t ws_size,
                              hipStream_t stream) {
  const int* edge_index = (const int*)d_in[0];
  const int* edge_type  = (const int*)d_in[1];
  const float* emb   = (const float*)d_in[2];
  const float* W1    = (const float*)d_in[3];
  const float* root1 = (const float*)d_in[4];
  const float* b1    = (const float*)d_in[5];
  const float* W2    = (const float*)d_in[6];
  const float* root2 = (const float*)d_in[7];
  const float* b2    = (const float*)d_in[8];
  float* out = (float*)d_out;

  int E = in_sizes[0] / 2;
  const int* src = edge_index;      // row 0
  const int* dst = edge_index + E;  // row 1
  int nblocks_seg = (N_SEG + 255) / 256;  // 3125

  char* ws = (char*)d_ws;
  size_t off_b = 0;
  auto take = [&](size_t bytes) -> char* {
    char* p = ws + off_b;
    off_b += (bytes + 255) & ~(size_t)255;
    return p;
  };
  int*   cnt    = (int*)take((size_t)N_SEG * 4);
  int*   offs   = (int*)take((size_t)(N_SEG + 1) * 4);
  int*   bsum   = (int*)take((size_t)nblocks_seg * 4);
  int*   bucket = (int*)take((size_t)E * 4);
  u16*   embb   = (u16*)take((size_t)N_NODES * D * 2);
  u16*   x1     = (u16*)take((size_t)N_NODES * D * 2);
  u16*   Wf1    = (u16*)take((size_t)64 * 8 * 512 * 2);
  u16*   Rf1    = (u16*)take((size_t)4 * 8 * 512 * 2);
  u16*   Wf2    = (u16*)take((size_t)64 * 8 * 512 * 2);
  u16*   Rf2    = (u16*)take((size_t)4 * 8 * 512 * 2);
  // total ~41 MB — fits comfortably

  int eBlocks = (E + 255) / 256;
  int layerBlocks = N_NODES / 16;   // 3125 blocks, 8 waves each -> 25K waves

  // --- CSR build (shared by both layers) ---
  k_zero4<<<512, 256, 0, stream>>>((uint4*)cnt, (long long)N_SEG * 4 / 16);
  k_count<<<eBlocks, 256, 0, stream>>>(dst, edge_type, cnt, E);
  k_bsum<<<nblocks_seg, 256, 0, stream>>>(cnt, bsum, N_SEG);
  k_bscan<<<1, 1024, 0, stream>>>(bsum, nblocks_seg);
  k_off<<<nblocks_seg, 256, 0, stream>>>(cnt, bsum, offs, N_SEG);
  k_fill<<<eBlocks, 256, 0, stream>>>(src, dst, edge_type, offs, cnt, bucket, E);

  // --- fused weight/embedding prep (single launch) ---
  k_prep<<<(PREP_TOTAL + 255) / 256, 256, 0, stream>>>(emb, embb, W1, Wf1, W2, Wf2,
                                                       root1, Rf1, root2, Rf2);

  // --- two fused layers ---
  k_layer<1><<<layerBlocks, 512, 0, stream>>>(offs, bucket, embb, Wf1, Rf1, b1,
                                              x1, nullptr);
  k_layer<2><<<layerBlocks, 512, 0, stream>>>(offs, bucket, x1, Wf2, Rf2, b2,
                                              nullptr, out);
}

// Round 9
// 511.588 us; speedup vs baseline: 1.1270x; 1.0332x over previous
//
#include <hip/hip_runtime.h>

#define N_NODES 50000
#define N_REL 16
#define D 128
#define N_SEG (N_NODES * N_REL)  // 800000
#define N_SEG4 (N_SEG / 4)       // 200000 int4 tiles of cnt

typedef short bf16x8 __attribute__((ext_vector_type(8)));
typedef float f32x4 __attribute__((ext_vector_type(4)));
typedef unsigned short u16;
typedef unsigned int u32;

__device__ __forceinline__ u16 f32_to_bf16(float f) {
  u32 u = __builtin_bit_cast(u32, f);
  u32 r = (u + 0x7FFFu + ((u >> 16) & 1u)) >> 16;
  return (u16)r;
}
__device__ __forceinline__ float bf16_to_f32(u16 h) {
  u32 u = ((u32)h) << 16;
  return __builtin_bit_cast(float, u);
}

// ---------------- per-(dst,rel) edge counts (2 edges/thread) ----------------
__global__ __launch_bounds__(256) void k_count(const int* __restrict__ dst,
                                               const int* __restrict__ rel,
                                               int* __restrict__ cnt, int E) {
  int e = (blockIdx.x * blockDim.x + threadIdx.x) * 2;
  if (e < E)     atomicAdd(&cnt[dst[e] * N_REL + rel[e]], 1);
  if (e + 1 < E) atomicAdd(&cnt[dst[e + 1] * N_REL + rel[e + 1]], 1);
}

// ---------------- scan stage 1: 1024-int tiles (int4), per-block sums ----------
__global__ __launch_bounds__(256) void k_bsum2(const int4* __restrict__ cnt4,
                                               int* __restrict__ bsum, int n4) {
  __shared__ int sm[256];
  int idx = blockIdx.x * 256 + threadIdx.x;
  int v = 0;
  if (idx < n4) { int4 c = cnt4[idx]; v = c.x + c.y + c.z + c.w; }
  sm[threadIdx.x] = v;
  __syncthreads();
  for (int s = 128; s > 0; s >>= 1) {
    if (threadIdx.x < s) sm[threadIdx.x] += sm[threadIdx.x + s];
    __syncthreads();
  }
  if (threadIdx.x == 0) bsum[blockIdx.x] = sm[0];
}

// ---------------- scan stage 2: single-iteration exclusive scan (nb <= 1024) ----
__global__ __launch_bounds__(1024) void k_bscan2(int* __restrict__ bsum, int nb) {
  __shared__ int sm[1024];
  int i = threadIdx.x;
  int v = (i < nb) ? bsum[i] : 0;
  sm[i] = v;
  __syncthreads();
  for (int s = 1; s < 1024; s <<= 1) {
    int t = (i >= s) ? sm[i - s] : 0;
    __syncthreads();
    sm[i] += t;
    __syncthreads();
  }
  if (i < nb) bsum[i] = sm[i] - v;   // exclusive
}

// ---------------- scan stage 3: int4 per-element exclusive offsets ----------------
__global__ __launch_bounds__(256) void k_off2(const int4* __restrict__ cnt4,
                                              const int* __restrict__ bsum,
                                              int* __restrict__ off, int n4) {
  __shared__ int sm[256];
  int idx = blockIdx.x * 256 + threadIdx.x;
  int4 c = {0, 0, 0, 0};
  if (idx < n4) c = cnt4[idx];
  int tsum = c.x + c.y + c.z + c.w;
  sm[threadIdx.x] = tsum;
  __syncthreads();
  for (int s = 1; s < 256; s <<= 1) {
    int t = (threadIdx.x >= s) ? sm[threadIdx.x - s] : 0;
    __syncthreads();
    sm[threadIdx.x] += t;
    __syncthreads();
  }
  int base = bsum[blockIdx.x] + sm[threadIdx.x] - tsum;
  if (idx < n4) {
    int4 o;
    o.x = base;
    o.y = base + c.x;
    o.z = o.y + c.y;
    o.w = o.z + c.z;
    ((int4*)off)[idx] = o;
    if (idx == n4 - 1) off[4 * n4] = o.w + c.w;  // off[N_SEG] = E
  }
}

// ---------------- CSR fill (countdown; 2 edges/thread) ----------------
__global__ __launch_bounds__(256) void k_fill(const int* __restrict__ src,
                                              const int* __restrict__ dst,
                                              const int* __restrict__ rel,
                                              const int* __restrict__ off,
                                              int* __restrict__ cnt,
                                              int* __restrict__ bucket, int E) {
  int e = (blockIdx.x * blockDim.x + threadIdx.x) * 2;
  if (e < E) {
    int seg = dst[e] * N_REL + rel[e];
    int old = atomicSub(&cnt[seg], 1);          // old in [1, cnt]
    bucket[off[seg] + old - 1] = src[e];
  }
  if (e + 1 < E) {
    int seg = dst[e + 1] * N_REL + rel[e + 1];
    int old = atomicSub(&cnt[seg], 1);
    bucket[off[seg] + old - 1] = src[e + 1];
  }
}

// ---------------- fused prep: cnt-zero + f32->bf16 convert + 4 weight-frag builds --
__device__ __forceinline__ void wfrag_one(const float* __restrict__ W,
                                          u16* __restrict__ Wf, int tid) {
  int lane = tid & 63;
  int t = (tid >> 6) & 7;
  int kb = tid >> 9;
  int h = t * 16 + (lane & 15);
  int kbase = kb * 32 + ((lane >> 4) << 3);
  bf16x8 frag;
#pragma unroll
  for (int j = 0; j < 8; ++j) {
    int k = kbase + j;
    frag[j] = (short)f32_to_bf16(W[(size_t)(k >> 7) * (D * D) + (size_t)(k & 127) * D + h]);
  }
  *(bf16x8*)(Wf + (size_t)tid * 8) = frag;
}

#define ZERO_U4 N_SEG4                   // 200,000 uint4 of cnt
#define CVT_N4 (N_NODES * D / 4)         // 1,600,000
#define WF_T (64 * 8 * 64)               // 32768
#define RF_T (4 * 8 * 64)                // 2048
#define PREP_TOTAL (ZERO_U4 + CVT_N4 + 2 * WF_T + 2 * RF_T)

__global__ __launch_bounds__(256) void k_prep(int* __restrict__ cnt,
                                              const float* __restrict__ emb,
                                              u16* __restrict__ embb,
                                              const float* __restrict__ W1,
                                              u16* __restrict__ Wf1,
                                              const float* __restrict__ W2,
                                              u16* __restrict__ Wf2,
                                              const float* __restrict__ R1,
                                              u16* __restrict__ Rf1,
                                              const float* __restrict__ R2,
                                              u16* __restrict__ Rf2) {
  int tid = blockIdx.x * blockDim.x + threadIdx.x;
  if (tid < ZERO_U4) {
    uint4 z; z.x = z.y = z.z = z.w = 0u;
    ((uint4*)cnt)[tid] = z;
    return;
  }
  int u = tid - ZERO_U4;
  if (u < CVT_N4) {
    float4 v = ((const float4*)emb)[u];
    u32 p0 = (u32)f32_to_bf16(v.x) | ((u32)f32_to_bf16(v.y) << 16);
    u32 p1 = (u32)f32_to_bf16(v.z) | ((u32)f32_to_bf16(v.w) << 16);
    ((u32*)embb)[u * 2] = p0;
    ((u32*)embb)[u * 2 + 1] = p1;
    return;
  }
  u -= CVT_N4;
  if (u < WF_T) { wfrag_one(W1, Wf1, u); return; }
  u -= WF_T;
  if (u < WF_T) { wfrag_one(W2, Wf2, u); return; }
  u -= WF_T;
  if (u < RF_T) { wfrag_one(R1, Rf1, u); return; }
  u -= RF_T;
  if (u < RF_T) { wfrag_one(R2, Rf2, u); return; }
}

// ---------------- fused RGCN layer (R5 shape — the measured best: 142 µs) ---------
// One 16-node M-tile per BLOCK, 4 waves, each owning 4 relations + 1 kb-quarter
// of the root term; gather-mean straight into A-fragment registers; MFMA vs
// frag-linear Wf; 16KB two-round LDS reduce; fused bias(+ReLU)+store.
// Rotated bucket-index prefetch keeps the next edge's index load off the
// per-edge serial chain. VGPR 56 — R6/R1 showed deeper prefetch (+16 regs)
// regresses via residency; do not add register pressure here.
template <int L>  // L=1: bf16 out + ReLU; L=2: f32 out
__global__ __launch_bounds__(256) void k_layer(const int* __restrict__ off,
                                               const int* __restrict__ bucket,
                                               const u16* __restrict__ x,    // [N,128] bf16
                                               const u16* __restrict__ Wf,   // 64 kb frag-linear
                                               const u16* __restrict__ Rf,   // 4 kb frag-linear
                                               const float* __restrict__ bias,
                                               u16* __restrict__ outb,
                                               float* __restrict__ outf) {
  __shared__ f32x4 red[4][4][64];      // 16 KB
  int w = threadIdx.x >> 6;            // wave 0..3
  int lane = threadIdx.x & 63;
  int node0 = blockIdx.x << 4;         // 50000 = 3125*16, exact grid
  int m = lane & 15;
  int q = lane >> 4;
  int node = node0 + m;                // A-row this lane serves

  f32x4 acc[8];
#pragma unroll
  for (int t = 0; t < 8; ++t)
#pragma unroll
    for (int i = 0; i < 4; ++i) acc[t][i] = 0.0f;

  // ---- root term: this wave does kb = w ----
  {
    bf16x8 a = *(const bf16x8*)(x + ((size_t)node << 7) + w * 32 + (q << 3));
    const u16* bp = Rf + ((size_t)w << 12) + ((size_t)lane << 3);
#pragma unroll
    for (int t = 0; t < 8; ++t) {
      bf16x8 b = *(const bf16x8*)(bp + t * 512);
      acc[t] = __builtin_amdgcn_mfma_f32_16x16x32_bf16(a, b, acc[t], 0, 0, 0);
    }
  }

  // ---- 4 relations per wave: gather-mean into A-frag regs, MFMA vs W_r ----
  for (int rr = 0; rr < 4; ++rr) {
    int r = (w << 2) + rr;
    int seg = (node << 4) + r;
    int o0 = off[seg];
    int o1 = off[seg + 1];

    float a0[8], a1[8], a2[8], a3[8];
#pragma unroll
    for (int j = 0; j < 8; ++j) { a0[j] = 0.f; a1[j] = 0.f; a2[j] = 0.f; a3[j] = 0.f; }

    // rotated prefetch: bucket[i+1] in flight while edge i's rows load/accumulate
    int i = o0;
    int s = (i < o1) ? bucket[i] : 0;
    while (i < o1) {                   // divergent across m; exec-masked
      const u16* xs = x + ((size_t)s << 7) + (q << 3);
      bf16x8 v0 = *(const bf16x8*)(xs);
      bf16x8 v1 = *(const bf16x8*)(xs + 32);
      bf16x8 v2 = *(const bf16x8*)(xs + 64);
      bf16x8 v3 = *(const bf16x8*)(xs + 96);
      int snext = (i + 1 < o1) ? bucket[i + 1] : 0;
#pragma unroll
      for (int j = 0; j < 8; ++j) {
        a0[j] += bf16_to_f32((u16)v0[j]);
        a1[j] += bf16_to_f32((u16)v1[j]);
        a2[j] += bf16_to_f32((u16)v2[j]);
        a3[j] += bf16_to_f32((u16)v3[j]);
      }
      s = snext;
      ++i;
    }

    float sc = (o1 > o0) ? 1.0f / (float)(o1 - o0) : 0.0f;
    bf16x8 f0, f1, f2, f3;
#pragma unroll
    for (int j = 0; j < 8; ++j) {
      f0[j] = (short)f32_to_bf16(a0[j] * sc);
      f1[j] = (short)f32_to_bf16(a1[j] * sc);
      f2[j] = (short)f32_to_bf16(a2[j] * sc);
      f3[j] = (short)f32_to_bf16(a3[j] * sc);
    }

    const u16* bp = Wf + ((size_t)(r * 4) << 12) + ((size_t)lane << 3);
#pragma unroll
    for (int t = 0; t < 8; ++t) {
      bf16x8 b0 = *(const bf16x8*)(bp + t * 512);
      bf16x8 b1 = *(const bf16x8*)(bp + 4096 + t * 512);
      bf16x8 b2 = *(const bf16x8*)(bp + 8192 + t * 512);
      bf16x8 b3 = *(const bf16x8*)(bp + 12288 + t * 512);
      acc[t] = __builtin_amdgcn_mfma_f32_16x16x32_bf16(f0, b0, acc[t], 0, 0, 0);
      acc[t] = __builtin_amdgcn_mfma_f32_16x16x32_bf16(f1, b1, acc[t], 0, 0, 0);
      acc[t] = __builtin_amdgcn_mfma_f32_16x16x32_bf16(f2, b2, acc[t], 0, 0, 0);
      acc[t] = __builtin_amdgcn_mfma_f32_16x16x32_bf16(f3, b3, acc[t], 0, 0, 0);
    }
  }

  // ---- two-round epilogue over 16KB red buffer ----
  // round h: waves write acc[4h..4h+3]; wave w reduces chunk t = 4h + w.
#pragma unroll
  for (int half = 0; half < 2; ++half) {
#pragma unroll
    for (int t = 0; t < 4; ++t) red[w][t][lane] = acc[half * 4 + t];
    __syncthreads();
    {
      f32x4 s0 = red[0][w][lane];
      f32x4 s1 = red[1][w][lane];
      f32x4 s2 = red[2][w][lane];
      f32x4 s3 = red[3][w][lane];
      int tt = half * 4 + w;
      int h = tt * 16 + m;             // C layout col=m, row=q*4+reg [m89]
      float bv = bias[h];
#pragma unroll
      for (int r4 = 0; r4 < 4; ++r4) {
        int n = node0 + (q << 2) + r4;
        float v = s0[r4] + s1[r4] + s2[r4] + s3[r4] + bv;
        if (L == 1) {
          v = v > 0.0f ? v : 0.0f;
          outb[(size_t)n * D + h] = f32_to_bf16(v);
        } else {
          outf[(size_t)n * D + h] = v;
        }
      }
    }
    if (half == 0) __syncthreads();    // WAR: round-A reads done before round-B writes
  }
}

extern "C" void kernel_launch(void* const* d_in, const int* in_sizes, int n_in,
                              void* d_out, int out_size, void* d_ws, size_t ws_size,
                              hipStream_t stream) {
  const int* edge_index = (const int*)d_in[0];
  const int* edge_type  = (const int*)d_in[1];
  const float* emb   = (const float*)d_in[2];
  const float* W1    = (const float*)d_in[3];
  const float* root1 = (const float*)d_in[4];
  const float* b1    = (const float*)d_in[5];
  const float* W2    = (const float*)d_in[6];
  const float* root2 = (const float*)d_in[7];
  const float* b2    = (const float*)d_in[8];
  float* out = (float*)d_out;

  int E = in_sizes[0] / 2;
  const int* src = edge_index;      // row 0
  const int* dst = edge_index + E;  // row 1
  int scanBlocks = (N_SEG4 + 255) / 256;  // 782 (1024-int tiles)

  char* ws = (char*)d_ws;
  size_t off_b = 0;
  auto take = [&](size_t bytes) -> char* {
    char* p = ws + off_b;
    off_b += (bytes + 255) & ~(size_t)255;
    return p;
  };
  int*   cnt    = (int*)take((size_t)N_SEG * 4);
  int*   offs   = (int*)take((size_t)(N_SEG + 1) * 4);
  int*   bsum   = (int*)take((size_t)scanBlocks * 4);
  int*   bucket = (int*)take((size_t)E * 4);
  u16*   embb   = (u16*)take((size_t)N_NODES * D * 2);
  u16*   x1     = (u16*)take((size_t)N_NODES * D * 2);
  u16*   Wf1    = (u16*)take((size_t)64 * 8 * 512 * 2);
  u16*   Rf1    = (u16*)take((size_t)4 * 8 * 512 * 2);
  u16*   Wf2    = (u16*)take((size_t)64 * 8 * 512 * 2);
  u16*   Rf2    = (u16*)take((size_t)4 * 8 * 512 * 2);
  // total ~41 MB — fits comfortably

  int eBlocks2 = ((E + 1) / 2 + 255) / 256;  // 2 edges/thread
  int layerBlocks = N_NODES / 16;            // 3125 blocks, 1 tile per block

  // --- fused prep (zeroes cnt + converts emb + builds all weight frags) ---
  k_prep<<<(PREP_TOTAL + 255) / 256, 256, 0, stream>>>(cnt, emb, embb, W1, Wf1,
                                                       W2, Wf2, root1, Rf1,
                                                       root2, Rf2);

  // --- CSR build (shared by both layers) ---
  k_count<<<eBlocks2, 256, 0, stream>>>(dst, edge_type, cnt, E);
  k_bsum2<<<scanBlocks, 256, 0, stream>>>((const int4*)cnt, bsum, N_SEG4);
  k_bscan2<<<1, 1024, 0, stream>>>(bsum, scanBlocks);
  k_off2<<<scanBlocks, 256, 0, stream>>>((const int4*)cnt, bsum, offs, N_SEG4);
  k_fill<<<eBlocks2, 256, 0, stream>>>(src, dst, edge_type, offs, cnt, bucket, E);

  // --- two fused layers ---
  k_layer<1><<<layerBlocks, 256, 0, stream>>>(offs, bucket, embb, Wf1, Rf1, b1,
                                              x1, nullptr);
  k_layer<2><<<layerBlocks, 256, 0, stream>>>(offs, bucket, x1, Wf2, Rf2, b2,
                                              nullptr, out);
}